// Round 2
// baseline (358.699 us; speedup 1.0000x reference)
//
#include <hip/hip_runtime.h>
#include <cmath>

#define NB 256
#define NS 8192
#define NF 2048
#define NK 20

typedef _Float16 half8 __attribute__((ext_vector_type(8)));
typedef _Float16 half4 __attribute__((ext_vector_type(4)));
typedef float f32x4 __attribute__((ext_vector_type(4)));

__device__ __forceinline__ void async16(const void* g, void* l) {
  __builtin_amdgcn_global_load_lds(
      (const __attribute__((address_space(1))) unsigned int*)g,
      (__attribute__((address_space(3))) unsigned int*)l, 16, 0, 0);
}

__device__ __forceinline__ float waveSum(float v) {
#pragma unroll
  for (int off = 32; off > 0; off >>= 1) v += __shfl_xor(v, off, 64);
  return v;
}
__device__ __forceinline__ float waveMax(float v) {
#pragma unroll
  for (int off = 32; off > 0; off >>= 1) v = fmaxf(v, __shfl_xor(v, off, 64));
  return v;
}

// ---- x = normalize(inputs0); fp32 + fp16 copies ----
__global__ __launch_bounds__(256) void normalize_x(const float* __restrict__ in0,
                                                   float* __restrict__ xf,
                                                   _Float16* __restrict__ xh) {
  __shared__ float red[4];
  int b = blockIdx.x, tid = threadIdx.x;
  const float4* row = (const float4*)(in0 + (size_t)b * NF);
  float4 v0 = row[tid], v1 = row[tid + 256];
  float ss = v0.x * v0.x + v0.y * v0.y + v0.z * v0.z + v0.w * v0.w +
             v1.x * v1.x + v1.y * v1.y + v1.z * v1.z + v1.w * v1.w;
  float w = waveSum(ss);
  int wave = tid >> 6, lane = tid & 63;
  if (lane == 0) red[wave] = w;
  __syncthreads();
  float tot = (red[0] + red[1]) + (red[2] + red[3]);
  float inv = 1.0f / fmaxf(sqrtf(tot), 1e-12f);
  float4 o0 = make_float4(v0.x * inv, v0.y * inv, v0.z * inv, v0.w * inv);
  float4 o1 = make_float4(v1.x * inv, v1.y * inv, v1.z * inv, v1.w * inv);
  ((float4*)(xf + (size_t)b * NF))[tid] = o0;
  ((float4*)(xf + (size_t)b * NF))[tid + 256] = o1;
  half4 h0, h1;
  h0[0] = (_Float16)o0.x; h0[1] = (_Float16)o0.y; h0[2] = (_Float16)o0.z; h0[3] = (_Float16)o0.w;
  h1[0] = (_Float16)o1.x; h1[1] = (_Float16)o1.y; h1[2] = (_Float16)o1.z; h1[3] = (_Float16)o1.w;
  ((half4*)(xh + (size_t)b * NF))[tid] = h0;
  ((half4*)(xh + (size_t)b * NF))[tid + 256] = h1;
}

// ---- per-row neighbor weights + inverse update map (last-occurrence wins) ----
__global__ __launch_bounds__(256) void prep_small(const int* __restrict__ targets,
                                                  const int* __restrict__ neighbors,
                                                  const float* __restrict__ ndist,
                                                  float4* __restrict__ nbw,
                                                  int* __restrict__ updrow) {
  int b = threadIdx.x;
  for (int i = b; i < NS; i += 256) updrow[i] = 0;
  __syncthreads();
  int tg = targets[b];
  int w = 1;
  for (int b2 = b + 1; b2 < NB; ++b2)
    if (targets[b2] == tg) { w = 0; break; }
  if (w) updrow[tg] = b + 1;

  float e[NK];
  float s = 0.0f;
  int cnt = 0;
  for (int k = 0; k < NK; ++k) {
    float d = ndist[b * NK + k];
    e[k] = expf(d * (1.0f / 0.6f));
    s += e[k];
    cnt += (d <= 2.0f) ? 1 : 0;
  }
  float invs = 1.0f / (2.0f * s);
  float invc = 1.0f / fmaxf((float)cnt, 1.0f);
  for (int k = 0; k < NK; ++k) {
    float d = ndist[b * NK + k];
    nbw[b * NK + k] = make_float4(__int_as_float(neighbors[b * NK + k]),
                                  e[k] * invs,
                                  (d <= 2.0f) ? invc : 0.0f, 0.0f);
  }
}

// ---- features -> out (with fused momentum update) + original fp16 copy ----
__global__ __launch_bounds__(256) void prep_features2(const float4* __restrict__ f,
                                                      const float* __restrict__ xf,
                                                      const int* __restrict__ updrow,
                                                      float* __restrict__ outF,
                                                      _Float16* __restrict__ fh) {
  __shared__ float red[4];
  int row = blockIdx.x, tid = threadIdx.x;
  const float4* fr = f + (size_t)row * (NF / 4);
  float4 v0 = fr[tid], v1 = fr[tid + 256];
  // fp16 copy of ORIGINAL features (scores use pre-update memory)
  half4 h0, h1;
  h0[0] = (_Float16)v0.x; h0[1] = (_Float16)v0.y; h0[2] = (_Float16)v0.z; h0[3] = (_Float16)v0.w;
  h1[0] = (_Float16)v1.x; h1[1] = (_Float16)v1.y; h1[2] = (_Float16)v1.z; h1[3] = (_Float16)v1.w;
  ((half4*)(fh + (size_t)row * NF))[tid] = h0;
  ((half4*)(fh + (size_t)row * NF))[tid + 256] = h1;

  int u = updrow[row];
  if (u) {  // block-uniform branch
    const float4* xr = (const float4*)(xf + (size_t)(u - 1) * NF);
    float4 a0 = xr[tid], a1 = xr[tid + 256];
    v0 = make_float4(0.2f * v0.x + 0.8f * a0.x, 0.2f * v0.y + 0.8f * a0.y,
                     0.2f * v0.z + 0.8f * a0.z, 0.2f * v0.w + 0.8f * a0.w);
    v1 = make_float4(0.2f * v1.x + 0.8f * a1.x, 0.2f * v1.y + 0.8f * a1.y,
                     0.2f * v1.z + 0.8f * a1.z, 0.2f * v1.w + 0.8f * a1.w);
    float ss = v0.x * v0.x + v0.y * v0.y + v0.z * v0.z + v0.w * v0.w +
               v1.x * v1.x + v1.y * v1.y + v1.z * v1.z + v1.w * v1.w;
    float w = waveSum(ss);
    int wave = tid >> 6, lane = tid & 63;
    if (lane == 0) red[wave] = w;
    __syncthreads();
    float tot = (red[0] + red[1]) + (red[2] + red[3]);
    float inv = 1.0f / fmaxf(sqrtf(tot), 1e-12f);
    v0.x *= inv; v0.y *= inv; v0.z *= inv; v0.w *= inv;
    v1.x *= inv; v1.y *= inv; v1.z *= inv; v1.w *= inv;
  }
  float* o = outF + (size_t)row * NF;
  int e0 = tid * 4, e1 = 1024 + tid * 4;
  o[e0 + 0] = v0.x; o[e0 + 1] = v0.y; o[e0 + 2] = v0.z; o[e0 + 3] = v0.w;
  o[e1 + 0] = v1.x; o[e1 + 1] = v1.y; o[e1 + 2] = v1.z; o[e1 + 3] = v1.w;
}

// ---- scores GEMM with fused per-stripe LSE partials (no scores written) ----
// tile 128(M) x 32(N), BK=32, grid (256 stripes, 2 M-blocks)
__global__ __launch_bounds__(256) void gemm_scores(const _Float16* __restrict__ xh,
                                                   const _Float16* __restrict__ fh,
                                                   float* __restrict__ pm,
                                                   float* __restrict__ pl) {
  __shared__ _Float16 As[128 * 32];  // 8 KB
  __shared__ _Float16 Bs[32 * 32];   // 2 KB
  int tid = threadIdx.x;
  int n0 = blockIdx.x * 32, m0 = blockIdx.y * 128;
  int wave = tid >> 6, lane = tid & 63, quad = lane >> 4, r16 = lane & 15;
  int wm = wave * 32;
  f32x4 acc[2][2] = {};

  int arow = tid >> 2, ach = tid & 3;
  for (int k0 = 0; k0 < NF; k0 += 32) {
    __syncthreads();
#pragma unroll
    for (int s = 0; s < 2; ++s) {
      int slot = s * 256 + tid;
      async16(xh + (size_t)(m0 + s * 64 + arow) * NF + k0 + ach * 8, &As[slot * 8]);
    }
    if (tid < 128)
      async16(fh + (size_t)(n0 + arow) * NF + k0 + ach * 8, &Bs[tid * 8]);
    __syncthreads();
    half8 af[2], bf[2];
#pragma unroll
    for (int i = 0; i < 2; ++i)
      af[i] = *(const half8*)&As[(wm + i * 16 + r16) * 32 + quad * 8];
#pragma unroll
    for (int j = 0; j < 2; ++j)
      bf[j] = *(const half8*)&Bs[(j * 16 + r16) * 32 + quad * 8];
#pragma unroll
    for (int i = 0; i < 2; ++i)
#pragma unroll
      for (int j = 0; j < 2; ++j)
        acc[i][j] = __builtin_amdgcn_mfma_f32_16x16x32_f16(af[i], bf[j], acc[i][j], 0, 0, 0);
  }
  // per-row (over this 32-col stripe) max + sumexp, scaled by 1/TEMP = 20
#pragma unroll
  for (int i = 0; i < 2; ++i)
#pragma unroll
    for (int r = 0; r < 4; ++r) {
      float s0 = acc[i][0][r] * 20.0f, s1 = acc[i][1][r] * 20.0f;
      float mx = fmaxf(s0, s1);
#pragma unroll
      for (int msk = 1; msk < 16; msk <<= 1) mx = fmaxf(mx, __shfl_xor(mx, msk, 64));
      float e = expf(s0 - mx) + expf(s1 - mx);
#pragma unroll
      for (int msk = 1; msk < 16; msk <<= 1) e += __shfl_xor(e, msk, 64);
      if (r16 == 0) {
        int R = m0 + wm + i * 16 + quad * 4 + r;
        pm[R * 256 + blockIdx.x] = mx;
        pl[R * 256 + blockIdx.x] = e;
      }
    }
}

// ---- combine LSE partials + target dot -> loss_nce accumulator ----
__global__ __launch_bounds__(256) void lse_combine(const float* __restrict__ pm,
                                                   const float* __restrict__ pl,
                                                   const _Float16* __restrict__ xh,
                                                   const _Float16* __restrict__ fh,
                                                   const int* __restrict__ targets,
                                                   float* __restrict__ acc) {
  __shared__ float redA[4], redB[4], redC[4];
  int b = blockIdx.x, tid = threadIdx.x;
  int wave = tid >> 6, lane = tid & 63;
  float m = pm[b * 256 + tid], l = pl[b * 256 + tid];
  float wmx = waveMax(m);
  if (lane == 0) redA[wave] = wmx;
  __syncthreads();
  float M = fmaxf(fmaxf(redA[0], redA[1]), fmaxf(redA[2], redA[3]));
  float le = l * expf(m - M);
  float wsm = waveSum(le);
  if (lane == 0) redB[wave] = wsm;
  // fp16 dot: x[b] . features[target_b]
  const half8* xr = (const half8*)(xh + (size_t)b * NF);
  const half8* fr = (const half8*)(fh + (size_t)targets[b] * NF);
  half8 a = xr[tid], c = fr[tid];
  float d = 0.0f;
#pragma unroll
  for (int i = 0; i < 8; ++i) d += (float)a[i] * (float)c[i];
  float wd = waveSum(d);
  if (lane == 0) redC[wave] = wd;
  __syncthreads();
  if (tid == 0) {
    float S = (redB[0] + redB[1]) + (redB[2] + redB[3]);
    float D = (redC[0] + redC[1]) + (redC[2] + redC[3]);
    atomicAdd(acc + 0, -(D * 20.0f - M - logf(S)));
  }
}

// ---- row max & sumexp for logits0 (rows 0..255) and logits1 (256..511) ----
__global__ __launch_bounds__(256) void row_stats(const float* __restrict__ logits0,
                                                 const float* __restrict__ logits1,
                                                 float* __restrict__ m_all,
                                                 float* __restrict__ l_all) {
  __shared__ float red[4];
  int r = blockIdx.x, tid = threadIdx.x;
  const float* src = (r < NB) ? logits0 : logits1;
  const float4* row = (const float4*)(src + (size_t)(r & (NB - 1)) * NS);
  float4 v[8];
  float mx = -1e30f;
#pragma unroll
  for (int i = 0; i < 8; ++i) {
    v[i] = row[tid + i * 256];
    mx = fmaxf(mx, fmaxf(fmaxf(v[i].x, v[i].y), fmaxf(v[i].z, v[i].w)));
  }
  float wv = waveMax(mx);
  int wave = tid >> 6, lane = tid & 63;
  if (lane == 0) red[wave] = wv;
  __syncthreads();
  float m = fmaxf(fmaxf(red[0], red[1]), fmaxf(red[2], red[3]));
  __syncthreads();
  float se = 0.0f;
#pragma unroll
  for (int i = 0; i < 8; ++i)
    se += expf(v[i].x - m) + expf(v[i].y - m) + expf(v[i].z - m) + expf(v[i].w - m);
  float sw = waveSum(se);
  if (lane == 0) red[wave] = sw;
  __syncthreads();
  float l = (red[0] + red[1]) + (red[2] + red[3]);
  if (tid == 0) { m_all[r] = m; l_all[r] = l; }
}

// ---- neighbor mixture losses: 16-col tiles, b-split 2, padded LDS ----
__global__ __launch_bounds__(256) void neighbor_losses(
    const float* __restrict__ logits0, const float* __restrict__ logits1,
    const float* __restrict__ m_all, const float* __restrict__ l_all,
    const float4* __restrict__ nbw, const int* __restrict__ targets,
    float* __restrict__ acc) {
  __shared__ float2 pq[NB * 17];  // 34 KB (pad +1 float2 per row)
  int tid = threadIdx.x;
  int c0 = blockIdx.x * 16;
  int b0 = blockIdx.y * 128;
  {
    int row = tid;
    float im0 = m_all[row], il0 = 1.0f / l_all[row];
    float im1 = m_all[NB + row], il1 = 1.0f / l_all[NB + row];
    const float4* r0 = (const float4*)(logits0 + (size_t)row * NS + c0);
    const float4* r1 = (const float4*)(logits1 + (size_t)row * NS + c0);
#pragma unroll
    for (int g = 0; g < 4; ++g) {
      float4 a = r0[g], c = r1[g];
      float2* dst = &pq[row * 17 + g * 4];
      dst[0] = make_float2(expf(a.x - im0) * il0, expf(c.x - im1) * il1);
      dst[1] = make_float2(expf(a.y - im0) * il0, expf(c.y - im1) * il1);
      dst[2] = make_float2(expf(a.z - im0) * il0, expf(c.z - im1) * il1);
      dst[3] = make_float2(expf(a.w - im0) * il0, expf(c.w - im1) * il1);
    }
  }
  __syncthreads();
  int wave = tid >> 6, lane = tid & 63, bq = lane >> 4, col = lane & 15;
  int gcol = c0 + col;
  float sce = 0.0f, skl = 0.0f;
  for (int it = 0; it < 8; ++it) {
    int b = b0 + wave * 32 + it * 4 + bq;
    const float4* nb = nbw + b * NK;
    float accl = 0.0f, acck = 0.0f;
#pragma unroll
    for (int k = 0; k < NK; ++k) {
      float4 q = nb[k];
      int n = __float_as_int(q.x);
      float2 p = pq[n * 17 + col];
      accl = fmaf(q.y, p.x + p.y, accl);
      acck = fmaf(q.z, p.x, acck);
    }
    float2 own = pq[b * 17 + col];
    float lp0 = logf(fmaxf(own.x, 1e-37f));
    float lp1 = logf(fmaxf(own.y, 1e-37f));
    float ce = -0.1f * accl * lp0;
    if (gcol == targets[b]) ce -= 0.9f * lp0;
    float klv = (acck > 0.0f) ? acck * (logf(fmaxf(acck, 1e-12f)) - lp1) : 0.0f;
    sce += ce;
    skl += klv;
  }
  sce = waveSum(sce);
  skl = waveSum(skl);
  if (lane == 0) {
    atomicAdd(acc + 1, sce);
    atomicAdd(acc + 2, skl);
  }
}

__global__ void finalize(const float* __restrict__ acc, const float* __restrict__ rampup,
                         float* __restrict__ out) {
  if (threadIdx.x == 0) {
    out[0] = acc[0] * (1.0f / 256.0f);
    out[1] = acc[1] * (1.0f / 256.0f);
    out[2] = rampup[0] * acc[2] * (1.0f / 256.0f);
  }
}

extern "C" void kernel_launch(void* const* d_in, const int* in_sizes, int n_in,
                              void* d_out, int out_size, void* d_ws, size_t ws_size,
                              hipStream_t stream) {
  const float* inputs0 = (const float*)d_in[0];
  const float* logits0 = (const float*)d_in[1];
  const float* logits1 = (const float*)d_in[2];
  const int* targets = (const int*)d_in[3];
  const int* neighbors = (const int*)d_in[5];
  const float* ndist = (const float*)d_in[6];
  const float* rampup = (const float*)d_in[7];
  const float* features = (const float*)d_in[8];
  float* out = (float*)d_out;

  char* ws = (char*)d_ws;
  float* acc = (float*)(ws);                    // 64 B
  int* updrow = (int*)(ws + 4096);              // 32 KB
  float4* nbw = (float4*)(ws + 65536);          // 80 KB
  float* m_all = (float*)(ws + 147456);         // 2 KB
  float* l_all = (float*)(ws + 149504);         // 2 KB
  float* pm = (float*)(ws + 262144);            // 256 KB
  float* pl = (float*)(ws + 524288);            // 256 KB
  float* xf = (float*)(ws + (1 << 20));         // 2 MB
  _Float16* xh = (_Float16*)(ws + (3 << 20));   // 1 MB
  _Float16* fh = (_Float16*)(ws + (4 << 20));   // 32 MB

  hipMemsetAsync(acc, 0, 64, stream);
  normalize_x<<<NB, 256, 0, stream>>>(inputs0, xf, xh);
  prep_small<<<1, 256, 0, stream>>>(targets, neighbors, ndist, nbw, updrow);
  prep_features2<<<NS, 256, 0, stream>>>((const float4*)features, xf, updrow, out + 3, fh);
  gemm_scores<<<dim3(NS / 32, 2), 256, 0, stream>>>(xh, fh, pm, pl);
  lse_combine<<<NB, 256, 0, stream>>>(pm, pl, xh, fh, targets, acc);
  row_stats<<<2 * NB, 256, 0, stream>>>(logits0, logits1, m_all, l_all);
  neighbor_losses<<<dim3(NS / 16, 2), 256, 0, stream>>>(logits0, logits1, m_all, l_all, nbw, targets, acc);
  finalize<<<1, 64, 0, stream>>>(acc, rampup, out);
}

// Round 3
// 299.241 us; speedup vs baseline: 1.1987x; 1.1987x over previous
//
#include <hip/hip_runtime.h>
#include <cmath>

#define NB 256
#define NS 8192
#define NF 2048
#define NK 20

typedef _Float16 half8 __attribute__((ext_vector_type(8)));
typedef _Float16 half4 __attribute__((ext_vector_type(4)));
typedef float f32x4 __attribute__((ext_vector_type(4)));

__device__ __forceinline__ void async16(const void* g, void* l) {
  __builtin_amdgcn_global_load_lds(
      (const __attribute__((address_space(1))) unsigned int*)g,
      (__attribute__((address_space(3))) unsigned int*)l, 16, 0, 0);
}

__device__ __forceinline__ float waveSum(float v) {
#pragma unroll
  for (int off = 32; off > 0; off >>= 1) v += __shfl_xor(v, off, 64);
  return v;
}
__device__ __forceinline__ float waveMax(float v) {
#pragma unroll
  for (int off = 32; off > 0; off >>= 1) v = fmaxf(v, __shfl_xor(v, off, 64));
  return v;
}

// ============ K1: prologue ============
// blocks 0..255: normalize x; 256..767: row stats for logits0/1; 768: small prep
__global__ __launch_bounds__(256) void prologue(
    const float* __restrict__ in0, const float* __restrict__ logits0,
    const float* __restrict__ logits1, const int* __restrict__ targets,
    const int* __restrict__ neighbors, const float* __restrict__ ndist,
    float* __restrict__ xf, _Float16* __restrict__ xh,
    float* __restrict__ m_all, float* __restrict__ linv, float* __restrict__ mll,
    _Float16* __restrict__ Wp, int* __restrict__ updrow) {
  __shared__ float red[4];
  int tid = threadIdx.x, blk = blockIdx.x;
  int wave = tid >> 6, lane = tid & 63;
  if (blk < NB) {
    // normalize_x
    int b = blk;
    const float4* row = (const float4*)(in0 + (size_t)b * NF);
    float4 v0 = row[tid], v1 = row[tid + 256];
    float ss = v0.x * v0.x + v0.y * v0.y + v0.z * v0.z + v0.w * v0.w +
               v1.x * v1.x + v1.y * v1.y + v1.z * v1.z + v1.w * v1.w;
    float w = waveSum(ss);
    if (lane == 0) red[wave] = w;
    __syncthreads();
    float tot = (red[0] + red[1]) + (red[2] + red[3]);
    float inv = 1.0f / fmaxf(sqrtf(tot), 1e-12f);
    float4 o0 = make_float4(v0.x * inv, v0.y * inv, v0.z * inv, v0.w * inv);
    float4 o1 = make_float4(v1.x * inv, v1.y * inv, v1.z * inv, v1.w * inv);
    ((float4*)(xf + (size_t)b * NF))[tid] = o0;
    ((float4*)(xf + (size_t)b * NF))[tid + 256] = o1;
    half4 h0, h1;
    h0[0] = (_Float16)o0.x; h0[1] = (_Float16)o0.y; h0[2] = (_Float16)o0.z; h0[3] = (_Float16)o0.w;
    h1[0] = (_Float16)o1.x; h1[1] = (_Float16)o1.y; h1[2] = (_Float16)o1.z; h1[3] = (_Float16)o1.w;
    ((half4*)(xh + (size_t)b * NF))[tid] = h0;
    ((half4*)(xh + (size_t)b * NF))[tid + 256] = h1;
  } else if (blk < 768) {
    // row_stats: r 0..511 (logits0 rows then logits1 rows)
    int r = blk - NB;
    const float* src = (r < NB) ? logits0 : logits1;
    const float4* row = (const float4*)(src + (size_t)(r & (NB - 1)) * NS);
    float4 v[8];
    float mx = -1e30f;
#pragma unroll
    for (int i = 0; i < 8; ++i) {
      v[i] = row[tid + i * 256];
      mx = fmaxf(mx, fmaxf(fmaxf(v[i].x, v[i].y), fmaxf(v[i].z, v[i].w)));
    }
    float wv = waveMax(mx);
    if (lane == 0) red[wave] = wv;
    __syncthreads();
    float m = fmaxf(fmaxf(red[0], red[1]), fmaxf(red[2], red[3]));
    __syncthreads();
    float se = 0.0f;
#pragma unroll
    for (int i = 0; i < 8; ++i)
      se += expf(v[i].x - m) + expf(v[i].y - m) + expf(v[i].z - m) + expf(v[i].w - m);
    float sw = waveSum(se);
    if (lane == 0) red[wave] = sw;
    __syncthreads();
    float l = (red[0] + red[1]) + (red[2] + red[3]);
    if (tid == 0) { m_all[r] = m; linv[r] = 1.0f / l; mll[r] = m + logf(l); }
  } else {
    // prep_small: zero W + updrow, winner scan, build dense weight rows
    float4* W4 = (float4*)Wp;
    for (int i = tid; i < 512 * 512 * 2 / 16; i += 256) W4[i] = make_float4(0, 0, 0, 0);
    for (int i = tid; i < NS; i += 256) updrow[i] = 0;
    __syncthreads();
    int b = tid;
    int tg = targets[b];
    int w = 1;
    for (int b2 = b + 1; b2 < NB; ++b2)
      if (targets[b2] == tg) { w = 0; break; }
    if (w) updrow[tg] = b + 1;

    float e[NK];
    int n[NK];
    float s = 0.0f;
    int cnt = 0;
    for (int k = 0; k < NK; ++k) {
      float d = ndist[b * NK + k];
      e[k] = expf(d * (1.0f / 0.6f));
      n[k] = neighbors[b * NK + k];
      s += e[k];
      cnt += (d <= 2.0f) ? 1 : 0;
    }
    float invs = 1.0f / (2.0f * s);
    float invc = 1.0f / fmaxf((float)cnt, 1.0f);
    _Float16* rkl = Wp + (size_t)b * 512;
    _Float16* rce = Wp + (size_t)(256 + b) * 512;
    for (int k = 0; k < NK; ++k) {
      bool first = true;
      for (int k2 = 0; k2 < k; ++k2)
        if (n[k2] == n[k]) { first = false; break; }
      if (!first) continue;
      float wsum = 0.0f, ksum = 0.0f;
      for (int k2 = k; k2 < NK; ++k2)
        if (n[k2] == n[k]) {
          float d2 = ndist[b * NK + k2];
          wsum += e[k2] * invs;
          ksum += (d2 <= 2.0f) ? invc : 0.0f;
        }
      rkl[n[k]] = (_Float16)ksum;
      rce[n[k]] = (_Float16)wsum;
      rce[256 + n[k]] = (_Float16)wsum;
    }
  }
}

// ============ K2: stage2 ============
// blocks 0..8191: features->out (momentum rows fused) + fp16 copy
// blocks 8192..8447: transpose-exp: Pt[s][k] fp16, k<256=p0, k>=256=p1
__global__ __launch_bounds__(256) void stage2(
    const float4* __restrict__ f4, const float* __restrict__ xf,
    const int* __restrict__ updrow, const float* __restrict__ logits0,
    const float* __restrict__ logits1, const float* __restrict__ m_all,
    const float* __restrict__ linv, float* __restrict__ outF,
    _Float16* __restrict__ fh, _Float16* __restrict__ Pt) {
  __shared__ float red[4];
  __shared__ alignas(16) _Float16 Lt[32 * 520];
  int tid = threadIdx.x, blk = blockIdx.x;
  if (blk < NS) {
    int row = blk;
    const float4* fr = f4 + (size_t)row * (NF / 4);
    float4 v0 = fr[tid], v1 = fr[tid + 256];
    half4 h0, h1;
    h0[0] = (_Float16)v0.x; h0[1] = (_Float16)v0.y; h0[2] = (_Float16)v0.z; h0[3] = (_Float16)v0.w;
    h1[0] = (_Float16)v1.x; h1[1] = (_Float16)v1.y; h1[2] = (_Float16)v1.z; h1[3] = (_Float16)v1.w;
    ((half4*)(fh + (size_t)row * NF))[tid] = h0;
    ((half4*)(fh + (size_t)row * NF))[tid + 256] = h1;

    int u = updrow[row];
    if (u) {
      const float4* xr = (const float4*)(xf + (size_t)(u - 1) * NF);
      float4 a0 = xr[tid], a1 = xr[tid + 256];
      v0 = make_float4(0.2f * v0.x + 0.8f * a0.x, 0.2f * v0.y + 0.8f * a0.y,
                       0.2f * v0.z + 0.8f * a0.z, 0.2f * v0.w + 0.8f * a0.w);
      v1 = make_float4(0.2f * v1.x + 0.8f * a1.x, 0.2f * v1.y + 0.8f * a1.y,
                       0.2f * v1.z + 0.8f * a1.z, 0.2f * v1.w + 0.8f * a1.w);
      float ss = v0.x * v0.x + v0.y * v0.y + v0.z * v0.z + v0.w * v0.w +
                 v1.x * v1.x + v1.y * v1.y + v1.z * v1.z + v1.w * v1.w;
      float w = waveSum(ss);
      int wave = tid >> 6, lane = tid & 63;
      if (lane == 0) red[wave] = w;
      __syncthreads();
      float tot = (red[0] + red[1]) + (red[2] + red[3]);
      float inv = 1.0f / fmaxf(sqrtf(tot), 1e-12f);
      v0.x *= inv; v0.y *= inv; v0.z *= inv; v0.w *= inv;
      v1.x *= inv; v1.y *= inv; v1.z *= inv; v1.w *= inv;
    }
    float* o = outF + (size_t)row * NF;
    int e0 = tid * 4, e1 = 1024 + tid * 4;
    o[e0 + 0] = v0.x; o[e0 + 1] = v0.y; o[e0 + 2] = v0.z; o[e0 + 3] = v0.w;
    o[e1 + 0] = v1.x; o[e1 + 1] = v1.y; o[e1 + 2] = v1.z; o[e1 + 3] = v1.w;
  } else {
    int s0 = (blk - NS) * 32;
    // phase 1: load 512 rows x 32 cols, exp-normalize, transpose into LDS
#pragma unroll
    for (int g = 0; g < 16; ++g) {
      int pos = g * 256 + tid;          // 0..4095 float4 slots
      int row = pos >> 3;               // 0..511  (g-uniform halves)
      int c4 = pos & 7;
      const float* src = ((row < NB) ? logits0 + (size_t)row * NS
                                     : logits1 + (size_t)(row - NB) * NS) + s0 + c4 * 4;
      float4 v = *(const float4*)src;
      float m = m_all[row], li = linv[row];
      Lt[(c4 * 4 + 0) * 520 + row] = (_Float16)(expf(v.x - m) * li);
      Lt[(c4 * 4 + 1) * 520 + row] = (_Float16)(expf(v.y - m) * li);
      Lt[(c4 * 4 + 2) * 520 + row] = (_Float16)(expf(v.z - m) * li);
      Lt[(c4 * 4 + 3) * 520 + row] = (_Float16)(expf(v.w - m) * li);
    }
    __syncthreads();
    // phase 2: write Pt rows (1 KB each) fully coalesced
    int srow = tid >> 3, seg = tid & 7;
    _Float16* dst = Pt + (size_t)(s0 + srow) * 512 + seg * 64;
    const _Float16* lsrc = &Lt[srow * 520 + seg * 64];
#pragma unroll
    for (int q = 0; q < 8; ++q)
      *(half8*)(dst + q * 8) = *(const half8*)(lsrc + q * 8);
  }
}

// ============ K3: both GEMMs ============
// blocks 0..255: scores = x@F^T fused stripe-LSE + target pick (tile 128x64, BK=64)
// blocks 256..511: T = Wfull@Pfull fused CE/KL epilogue (tile 128x128, BK=64)
__global__ __launch_bounds__(256) void gemms(
    const _Float16* __restrict__ xh, const _Float16* __restrict__ fh,
    const _Float16* __restrict__ Wp, const _Float16* __restrict__ Pt,
    const float* __restrict__ logits0, const float* __restrict__ logits1,
    const float* __restrict__ mll, const int* __restrict__ targets,
    float* __restrict__ pm, float* __restrict__ pl, float* __restrict__ tgt,
    float* __restrict__ part) {
  __shared__ alignas(16) _Float16 As[128 * 64];
  __shared__ alignas(16) _Float16 Bs[128 * 64];
  __shared__ float red[4];
  int tid = threadIdx.x, wave = tid >> 6, lane = tid & 63;
  int quad = lane >> 4, r16 = lane & 15, lrow = lane >> 3, lch = lane & 7;
  int blk = blockIdx.x;
  if (blk < 256) {
    int bx = blk & 127, by = blk >> 7;
    int n0 = bx * 64, m0 = by * 128;
    f32x4 acc[2][4] = {};
    for (int k0 = 0; k0 < NF; k0 += 64) {
      __syncthreads();
#pragma unroll
      for (int ss = 0; ss < 4; ++ss) {
        int rl = ss * 32 + wave * 8 + lrow;
        int sc = lch ^ (rl & 7);
        async16(xh + (size_t)(m0 + rl) * NF + k0 + sc * 8, &As[rl * 64 + lch * 8]);
      }
#pragma unroll
      for (int ss = 0; ss < 2; ++ss) {
        int rl = ss * 32 + wave * 8 + lrow;
        int sc = lch ^ (rl & 7);
        async16(fh + (size_t)(n0 + rl) * NF + k0 + sc * 8, &Bs[rl * 64 + lch * 8]);
      }
      __syncthreads();
#pragma unroll
      for (int sub = 0; sub < 2; ++sub) {
        int slot = ((sub * 4 + quad) ^ (r16 & 7)) * 8;
        half8 af[2], bf[4];
#pragma unroll
        for (int i = 0; i < 2; ++i)
          af[i] = *(const half8*)&As[(wave * 32 + i * 16 + r16) * 64 + slot];
#pragma unroll
        for (int j = 0; j < 4; ++j)
          bf[j] = *(const half8*)&Bs[(j * 16 + r16) * 64 + slot];
#pragma unroll
        for (int i = 0; i < 2; ++i)
#pragma unroll
          for (int j = 0; j < 4; ++j)
            acc[i][j] = __builtin_amdgcn_mfma_f32_16x16x32_f16(af[i], bf[j], acc[i][j], 0, 0, 0);
      }
    }
#pragma unroll
    for (int i = 0; i < 2; ++i)
#pragma unroll
      for (int r = 0; r < 4; ++r) {
        int R = m0 + wave * 32 + i * 16 + quad * 4 + r;
        float sv[4];
#pragma unroll
        for (int j = 0; j < 4; ++j) sv[j] = acc[i][j][r] * 20.0f;  // 1/TEMP
        float mx = fmaxf(fmaxf(sv[0], sv[1]), fmaxf(sv[2], sv[3]));
#pragma unroll
        for (int m2 = 1; m2 < 16; m2 <<= 1) mx = fmaxf(mx, __shfl_xor(mx, m2, 64));
        float e = expf(sv[0] - mx) + expf(sv[1] - mx) + expf(sv[2] - mx) + expf(sv[3] - mx);
#pragma unroll
        for (int m2 = 1; m2 < 16; m2 <<= 1) e += __shfl_xor(e, m2, 64);
        int tg = targets[R];
#pragma unroll
        for (int j = 0; j < 4; ++j)
          if (n0 + j * 16 + r16 == tg) tgt[R] = sv[j];
        if (r16 == 0) { pm[bx * 256 + R] = mx; pl[bx * 256 + R] = e; }
      }
  } else {
    int nb = blk - 256;
    int bx = nb & 63, by = nb >> 6;
    int n0 = bx * 128, m0 = by * 128;
    int wm = (wave >> 1) * 64, wn = (wave & 1) * 64;
    f32x4 acc[4][4] = {};
    for (int k0 = 0; k0 < 512; k0 += 64) {
      __syncthreads();
#pragma unroll
      for (int ss = 0; ss < 4; ++ss) {
        int rl = ss * 32 + wave * 8 + lrow;
        int sc = lch ^ (rl & 7);
        async16(Wp + (size_t)(m0 + rl) * 512 + k0 + sc * 8, &As[rl * 64 + lch * 8]);
        async16(Pt + (size_t)(n0 + rl) * 512 + k0 + sc * 8, &Bs[rl * 64 + lch * 8]);
      }
      __syncthreads();
#pragma unroll
      for (int sub = 0; sub < 2; ++sub) {
        int slot = ((sub * 4 + quad) ^ (r16 & 7)) * 8;
        half8 af[4], bf[4];
#pragma unroll
        for (int i = 0; i < 4; ++i)
          af[i] = *(const half8*)&As[(wm + i * 16 + r16) * 64 + slot];
#pragma unroll
        for (int j = 0; j < 4; ++j)
          bf[j] = *(const half8*)&Bs[(wn + j * 16 + r16) * 64 + slot];
#pragma unroll
        for (int i = 0; i < 4; ++i)
#pragma unroll
          for (int j = 0; j < 4; ++j)
            acc[i][j] = __builtin_amdgcn_mfma_f32_16x16x32_f16(af[i], bf[j], acc[i][j], 0, 0, 0);
      }
    }
    bool iskl = (by < 2);
    const float* lgbase = iskl ? logits1 : logits0;
    float local = 0.0f;
#pragma unroll
    for (int i = 0; i < 4; ++i)
#pragma unroll
      for (int r = 0; r < 4; ++r) {
        int Mg = m0 + wm + i * 16 + quad * 4 + r;
        int b = iskl ? Mg : (Mg - 256);
        float mv = mll[iskl ? 256 + b : b];
        const float* lgrow = lgbase + (size_t)b * NS + n0 + wn;
#pragma unroll
        for (int j = 0; j < 4; ++j) {
          float lg = lgrow[j * 16 + r16];
          float t = acc[i][j][r];
          if (iskl)
            local += (t > 0.0f) ? t * (logf(fmaxf(t, 1e-12f)) - (lg - mv)) : 0.0f;
          else
            local += -0.1f * t * (lg - mv);
        }
      }
    float wsv = waveSum(local);
    if (lane == 0) red[wave] = wsv;
    __syncthreads();
    if (tid == 0) part[nb] = (red[0] + red[1]) + (red[2] + red[3]);
  }
}

// ============ K4: finalize (single block) ============
__global__ __launch_bounds__(256) void final_reduce(
    const float* __restrict__ pm, const float* __restrict__ pl,
    const float* __restrict__ tgt, const float* __restrict__ part,
    const float* __restrict__ logits0, const float* __restrict__ mll,
    const int* __restrict__ targets, const float* __restrict__ rampup,
    float* __restrict__ out) {
  __shared__ float rA[4], rB[4], rC[4], rD[4];
  int tid = threadIdx.x, wave = tid >> 6, lane = tid & 63;
  int b = tid;
  float mx = -1e30f;
  for (int s = 0; s < 128; ++s) mx = fmaxf(mx, pm[s * 256 + b]);
  float S = 0.0f;
  for (int s = 0; s < 128; ++s) S += pl[s * 256 + b] * expf(pm[s * 256 + b] - mx);
  float nce = -(tgt[b] - mx - logf(S));
  int tg = targets[b];
  float oh = -0.9f * (logits0[(size_t)b * NS + tg] - mll[b]);
  float c = part[tid];
  float klc = (tid < 128) ? c : 0.0f;
  float cec = (tid < 128) ? 0.0f : c;
  float wn_ = waveSum(nce), wo = waveSum(oh), wk = waveSum(klc), wc = waveSum(cec);
  if (lane == 0) { rA[wave] = wn_; rB[wave] = wo; rC[wave] = wk; rD[wave] = wc; }
  __syncthreads();
  if (tid == 0) {
    float sn = rA[0] + rA[1] + rA[2] + rA[3];
    float so = rB[0] + rB[1] + rB[2] + rB[3];
    float sk = rC[0] + rC[1] + rC[2] + rC[3];
    float sc2 = rD[0] + rD[1] + rD[2] + rD[3];
    out[0] = sn * (1.0f / 256.0f);
    out[1] = (so + sc2) * (1.0f / 256.0f);
    out[2] = rampup[0] * sk * (1.0f / 256.0f);
  }
}

extern "C" void kernel_launch(void* const* d_in, const int* in_sizes, int n_in,
                              void* d_out, int out_size, void* d_ws, size_t ws_size,
                              hipStream_t stream) {
  const float* inputs0 = (const float*)d_in[0];
  const float* logits0 = (const float*)d_in[1];
  const float* logits1 = (const float*)d_in[2];
  const int* targets = (const int*)d_in[3];
  const int* neighbors = (const int*)d_in[5];
  const float* ndist = (const float*)d_in[6];
  const float* rampup = (const float*)d_in[7];
  const float* features = (const float*)d_in[8];
  float* out = (float*)d_out;

  char* ws = (char*)d_ws;
  float* m_all = (float*)(ws + 0);              // 2 KB
  float* linv = (float*)(ws + 2048);            // 2 KB
  float* mll = (float*)(ws + 4096);             // 2 KB
  int* updrow = (int*)(ws + 8192);              // 32 KB
  float* part = (float*)(ws + 40960);           // 1 KB
  float* tgt = (float*)(ws + 43008);            // 1 KB
  float* pm = (float*)(ws + 65536);             // 128 KB
  float* pl = (float*)(ws + 196608);            // 128 KB
  _Float16* Wp = (_Float16*)(ws + 524288);      // 512 KB
  float* xf = (float*)(ws + (1 << 20));         // 2 MB
  _Float16* xh = (_Float16*)(ws + (3 << 20));   // 1 MB
  _Float16* Pt = (_Float16*)(ws + (4 << 20));   // 8 MB
  _Float16* fh = (_Float16*)(ws + (12 << 20));  // 32 MB

  prologue<<<769, 256, 0, stream>>>(inputs0, logits0, logits1, targets, neighbors,
                                    ndist, xf, xh, m_all, linv, mll, Wp, updrow);
  stage2<<<NS + 256, 256, 0, stream>>>((const float4*)features, xf, updrow, logits0,
                                       logits1, m_all, linv, out + 3, fh, Pt);
  gemms<<<512, 256, 0, stream>>>(xh, fh, Wp, Pt, logits0, logits1, mll, targets,
                                 pm, pl, tgt, part);
  final_reduce<<<1, 256, 0, stream>>>(pm, pl, tgt, part, logits0, mll, targets,
                                      rampup, out);
}

// Round 4
// 223.035 us; speedup vs baseline: 1.6083x; 1.3417x over previous
//
#include <hip/hip_runtime.h>
#include <cmath>

#define NB 256
#define NS 8192
#define NF 2048
#define NK 20

typedef _Float16 half8 __attribute__((ext_vector_type(8)));
typedef _Float16 half4 __attribute__((ext_vector_type(4)));
typedef float f32x4 __attribute__((ext_vector_type(4)));

__device__ __forceinline__ void async16(const void* g, void* l) {
  __builtin_amdgcn_global_load_lds(
      (const __attribute__((address_space(1))) unsigned int*)g,
      (__attribute__((address_space(3))) unsigned int*)l, 16, 0, 0);
}

__device__ __forceinline__ float waveSum(float v) {
#pragma unroll
  for (int off = 32; off > 0; off >>= 1) v += __shfl_xor(v, off, 64);
  return v;
}
__device__ __forceinline__ float waveMax(float v) {
#pragma unroll
  for (int off = 32; off > 0; off >>= 1) v = fmaxf(v, __shfl_xor(v, off, 64));
  return v;
}

// ============ K1: prep (everything independent, one dispatch) ============
// blocks [0,8192): features row copy -> out (+momentum winner rows) + fp16 fh
// blocks [8192,8704): row stats -> mll, alpha_h
// blocks [8704,8960): Pt transpose, RAW exp fp16
// blocks [8960,9216): normalize x -> xh fp16
// block 9216: zero Wp + build neighbor-weight rows (registers only)
__global__ __launch_bounds__(256, 1) void prep(
    const float4* __restrict__ f4, const float* __restrict__ in0,
    const float* __restrict__ logits0, const float* __restrict__ logits1,
    const int* __restrict__ targets, const int* __restrict__ neighbors,
    const float* __restrict__ ndist,
    float* __restrict__ outF, _Float16* __restrict__ fh,
    _Float16* __restrict__ Pt, _Float16* __restrict__ xh,
    _Float16* __restrict__ alpha_h, float* __restrict__ mll,
    _Float16* __restrict__ Wp) {
  __shared__ alignas(16) union {
    struct {
      float redA[4];
      float redB[4];
      unsigned long long wmask[4];
    } s;
    _Float16 Lt[32 * 520];
  } sm;
  int tid = threadIdx.x, blk = blockIdx.x;
  int wave = tid >> 6, lane = tid & 63;

  if (blk < NS) {
    // ---- features row ----
    int row = blk;
    const float4* fr = f4 + (size_t)row * (NF / 4);
    float4 v0 = fr[tid], v1 = fr[tid + 256];
    half4 h0, h1;
    h0[0] = (_Float16)v0.x; h0[1] = (_Float16)v0.y; h0[2] = (_Float16)v0.z; h0[3] = (_Float16)v0.w;
    h1[0] = (_Float16)v1.x; h1[1] = (_Float16)v1.y; h1[2] = (_Float16)v1.z; h1[3] = (_Float16)v1.w;
    ((half4*)(fh + (size_t)row * NF))[tid] = h0;
    ((half4*)(fh + (size_t)row * NF))[tid + 256] = h1;
    // winner = last b with targets[b]==row (ballot, no O(B^2) scan)
    unsigned long long mk = __ballot(targets[tid] == row);
    if (lane == 0) sm.s.wmask[wave] = mk;
    __syncthreads();
    int u = -1;
#pragma unroll
    for (int w = 3; w >= 0; --w)
      if (u < 0 && sm.s.wmask[w])
        u = w * 64 + 63 - (int)__clzll(sm.s.wmask[w]);
    if (u >= 0) {  // block-uniform
      const float4* xr = (const float4*)(in0 + (size_t)u * NF);
      float4 a0 = xr[tid], a1 = xr[tid + 256];
      float ssx = a0.x * a0.x + a0.y * a0.y + a0.z * a0.z + a0.w * a0.w +
                  a1.x * a1.x + a1.y * a1.y + a1.z * a1.z + a1.w * a1.w;
      float w1 = waveSum(ssx);
      if (lane == 0) sm.s.redA[wave] = w1;
      __syncthreads();
      float totx = (sm.s.redA[0] + sm.s.redA[1]) + (sm.s.redA[2] + sm.s.redA[3]);
      float ix = 0.8f / fmaxf(sqrtf(totx), 1e-12f);  // fold 0.8 into inv-norm
      v0 = make_float4(0.2f * v0.x + ix * a0.x, 0.2f * v0.y + ix * a0.y,
                       0.2f * v0.z + ix * a0.z, 0.2f * v0.w + ix * a0.w);
      v1 = make_float4(0.2f * v1.x + ix * a1.x, 0.2f * v1.y + ix * a1.y,
                       0.2f * v1.z + ix * a1.z, 0.2f * v1.w + ix * a1.w);
      float ss = v0.x * v0.x + v0.y * v0.y + v0.z * v0.z + v0.w * v0.w +
                 v1.x * v1.x + v1.y * v1.y + v1.z * v1.z + v1.w * v1.w;
      float w2 = waveSum(ss);
      if (lane == 0) sm.s.redB[wave] = w2;
      __syncthreads();
      float tot = (sm.s.redB[0] + sm.s.redB[1]) + (sm.s.redB[2] + sm.s.redB[3]);
      float inv = 1.0f / fmaxf(sqrtf(tot), 1e-12f);
      v0.x *= inv; v0.y *= inv; v0.z *= inv; v0.w *= inv;
      v1.x *= inv; v1.y *= inv; v1.z *= inv; v1.w *= inv;
    }
    float* o = outF + (size_t)row * NF;
    int e0 = tid * 4, e1 = 1024 + tid * 4;
    o[e0 + 0] = v0.x; o[e0 + 1] = v0.y; o[e0 + 2] = v0.z; o[e0 + 3] = v0.w;
    o[e1 + 0] = v1.x; o[e1 + 1] = v1.y; o[e1 + 2] = v1.z; o[e1 + 3] = v1.w;
  } else if (blk < NS + 512) {
    // ---- row stats ----
    int r = blk - NS;
    const float* src = (r < NB) ? logits0 : logits1;
    const float4* row = (const float4*)(src + (size_t)(r & (NB - 1)) * NS);
    float4 v[8];
    float mx = -1e30f;
#pragma unroll
    for (int i = 0; i < 8; ++i) {
      v[i] = row[tid + i * 256];
      mx = fmaxf(mx, fmaxf(fmaxf(v[i].x, v[i].y), fmaxf(v[i].z, v[i].w)));
    }
    float wv = waveMax(mx);
    if (lane == 0) sm.s.redA[wave] = wv;
    __syncthreads();
    float m = fmaxf(fmaxf(sm.s.redA[0], sm.s.redA[1]), fmaxf(sm.s.redA[2], sm.s.redA[3]));
    float se = 0.0f;
#pragma unroll
    for (int i = 0; i < 8; ++i)
      se += expf(v[i].x - m) + expf(v[i].y - m) + expf(v[i].z - m) + expf(v[i].w - m);
    float sw = waveSum(se);
    if (lane == 0) sm.s.redB[wave] = sw;
    __syncthreads();
    float l = (sm.s.redB[0] + sm.s.redB[1]) + (sm.s.redB[2] + sm.s.redB[3]);
    if (tid == 0) {
      mll[r] = m + logf(l);
      alpha_h[r] = (_Float16)(256.0f * expf(-m) / l);
    }
  } else if (blk < NS + 768) {
    // ---- Pt transpose (raw exp) ----
    int s0 = (blk - (NS + 512)) * 32;
#pragma unroll
    for (int g = 0; g < 16; ++g) {
      int pos = g * 256 + tid;
      int row = pos >> 3, c4 = pos & 7;
      const float* src = ((row < NB) ? logits0 + (size_t)row * NS
                                     : logits1 + (size_t)(row - NB) * NS) + s0 + c4 * 4;
      float4 v = *(const float4*)src;
      sm.Lt[(c4 * 4 + 0) * 520 + row] = (_Float16)expf(v.x);
      sm.Lt[(c4 * 4 + 1) * 520 + row] = (_Float16)expf(v.y);
      sm.Lt[(c4 * 4 + 2) * 520 + row] = (_Float16)expf(v.z);
      sm.Lt[(c4 * 4 + 3) * 520 + row] = (_Float16)expf(v.w);
    }
    __syncthreads();
    int srow = tid >> 3, seg = tid & 7;
    _Float16* dst = Pt + (size_t)(s0 + srow) * 512 + seg * 64;
    const _Float16* lsrc = &sm.Lt[srow * 520 + seg * 64];
#pragma unroll
    for (int q = 0; q < 8; ++q)
      *(half8*)(dst + q * 8) = *(const half8*)(lsrc + q * 8);
  } else if (blk < NS + 1024) {
    // ---- normalize x -> xh ----
    int b = blk - (NS + 768);
    const float4* row = (const float4*)(in0 + (size_t)b * NF);
    float4 v0 = row[tid], v1 = row[tid + 256];
    float ss = v0.x * v0.x + v0.y * v0.y + v0.z * v0.z + v0.w * v0.w +
               v1.x * v1.x + v1.y * v1.y + v1.z * v1.z + v1.w * v1.w;
    float w = waveSum(ss);
    if (lane == 0) sm.s.redA[wave] = w;
    __syncthreads();
    float tot = (sm.s.redA[0] + sm.s.redA[1]) + (sm.s.redA[2] + sm.s.redA[3]);
    float inv = 1.0f / fmaxf(sqrtf(tot), 1e-12f);
    half4 h0, h1;
    h0[0] = (_Float16)(v0.x * inv); h0[1] = (_Float16)(v0.y * inv);
    h0[2] = (_Float16)(v0.z * inv); h0[3] = (_Float16)(v0.w * inv);
    h1[0] = (_Float16)(v1.x * inv); h1[1] = (_Float16)(v1.y * inv);
    h1[2] = (_Float16)(v1.z * inv); h1[3] = (_Float16)(v1.w * inv);
    ((half4*)(xh + (size_t)b * NF))[tid] = h0;
    ((half4*)(xh + (size_t)b * NF))[tid + 256] = h1;
  } else {
    // ---- weight-matrix build (one block, registers only) ----
    float4* W4 = (float4*)Wp;
    for (int i = tid; i < 512 * 512 * 2 / 16; i += 256) W4[i] = make_float4(0, 0, 0, 0);
    __syncthreads();
    int b = tid;
    float d[NK], e[NK];
    int n[NK];
    float s = 0.0f;
    int cnt = 0;
#pragma unroll
    for (int k = 0; k < NK; ++k) {
      d[k] = ndist[b * NK + k];
      n[k] = neighbors[b * NK + k];
      e[k] = expf(d[k] * (1.0f / 0.6f));
      s += e[k];
      cnt += (d[k] <= 2.0f) ? 1 : 0;
    }
    float invs = 1.0f / (2.0f * s);
    float invc = 1.0f / fmaxf((float)cnt, 1.0f);
    _Float16* rkl = Wp + (size_t)b * 512;
    _Float16* rce = Wp + (size_t)(256 + b) * 512;
#pragma unroll
    for (int k = 0; k < NK; ++k) {
      bool first = true;
#pragma unroll
      for (int k2 = 0; k2 < NK; ++k2)
        if (k2 < k && n[k2] == n[k]) first = false;
      if (first) {
        float wsum = 0.0f, ksum = 0.0f;
#pragma unroll
        for (int k2 = 0; k2 < NK; ++k2)
          if (k2 >= k && n[k2] == n[k]) {
            wsum += e[k2] * invs;
            ksum += (d[k2] <= 2.0f) ? invc : 0.0f;
          }
        rkl[n[k]] = (_Float16)ksum;
        rce[n[k]] = (_Float16)wsum;
        rce[256 + n[k]] = (_Float16)wsum;
      }
    }
  }
}

// ============ K2: both GEMMs ============
// blocks [0,256): scores = x@F^T fused stripe-LSE + target pick (128x64, BK=64)
// blocks [256,512): T = W@P fused CE/KL epilogue (128x128, BK=64, alpha B-scale)
__global__ __launch_bounds__(256) void gemms(
    const _Float16* __restrict__ xh, const _Float16* __restrict__ fh,
    const _Float16* __restrict__ Wp, const _Float16* __restrict__ Pt,
    const _Float16* __restrict__ alpha_h,
    const float* __restrict__ logits0, const float* __restrict__ logits1,
    const float* __restrict__ mll, const int* __restrict__ targets,
    float* __restrict__ pm, float* __restrict__ pl, float* __restrict__ tgt,
    float* __restrict__ part) {
  __shared__ alignas(16) _Float16 As[128 * 64];
  __shared__ alignas(16) _Float16 Bs[128 * 64];
  __shared__ alignas(16) _Float16 Al[512];
  __shared__ float red[4];
  int tid = threadIdx.x, wave = tid >> 6, lane = tid & 63;
  int quad = lane >> 4, r16 = lane & 15, lrow = lane >> 3, lch = lane & 7;
  int blk = blockIdx.x;
  if (blk < 256) {
    int bx = blk & 127, by = blk >> 7;
    int n0 = bx * 64, m0 = by * 128;
    f32x4 acc[2][4] = {};
    for (int k0 = 0; k0 < NF; k0 += 64) {
      __syncthreads();
#pragma unroll
      for (int ss = 0; ss < 4; ++ss) {
        int rl = ss * 32 + wave * 8 + lrow;
        int sc = lch ^ (rl & 7);
        async16(xh + (size_t)(m0 + rl) * NF + k0 + sc * 8, &As[rl * 64 + lch * 8]);
      }
#pragma unroll
      for (int ss = 0; ss < 2; ++ss) {
        int rl = ss * 32 + wave * 8 + lrow;
        int sc = lch ^ (rl & 7);
        async16(fh + (size_t)(n0 + rl) * NF + k0 + sc * 8, &Bs[rl * 64 + lch * 8]);
      }
      __syncthreads();
#pragma unroll
      for (int sub = 0; sub < 2; ++sub) {
        int slot = ((sub * 4 + quad) ^ (r16 & 7)) * 8;
        half8 af[2], bf[4];
#pragma unroll
        for (int i = 0; i < 2; ++i)
          af[i] = *(const half8*)&As[(wave * 32 + i * 16 + r16) * 64 + slot];
#pragma unroll
        for (int j = 0; j < 4; ++j)
          bf[j] = *(const half8*)&Bs[(j * 16 + r16) * 64 + slot];
#pragma unroll
        for (int i = 0; i < 2; ++i)
#pragma unroll
          for (int j = 0; j < 4; ++j)
            acc[i][j] = __builtin_amdgcn_mfma_f32_16x16x32_f16(af[i], bf[j], acc[i][j], 0, 0, 0);
      }
    }
#pragma unroll
    for (int i = 0; i < 2; ++i)
#pragma unroll
      for (int r = 0; r < 4; ++r) {
        int R = m0 + wave * 32 + i * 16 + quad * 4 + r;
        float sv[4];
#pragma unroll
        for (int j = 0; j < 4; ++j) sv[j] = acc[i][j][r] * 20.0f;  // 1/TEMP
        float mx = fmaxf(fmaxf(sv[0], sv[1]), fmaxf(sv[2], sv[3]));
#pragma unroll
        for (int m2 = 1; m2 < 16; m2 <<= 1) mx = fmaxf(mx, __shfl_xor(mx, m2, 64));
        float e = expf(sv[0] - mx) + expf(sv[1] - mx) + expf(sv[2] - mx) + expf(sv[3] - mx);
#pragma unroll
        for (int m2 = 1; m2 < 16; m2 <<= 1) e += __shfl_xor(e, m2, 64);
        int tg = targets[R];
#pragma unroll
        for (int j = 0; j < 4; ++j)
          if (n0 + j * 16 + r16 == tg) tgt[R] = sv[j];
        if (r16 == 0) { pm[R * 128 + bx] = mx; pl[R * 128 + bx] = e; }
      }
  } else {
    int nb = blk - 256;
    int bx = nb & 63, by = nb >> 6;
    int n0 = bx * 128, m0 = by * 128;
    int wm = (wave >> 1) * 64, wn = (wave & 1) * 64;
    if (tid < 64) ((half8*)Al)[tid] = ((const half8*)alpha_h)[tid];
    f32x4 acc[4][4] = {};
    for (int k0 = 0; k0 < 512; k0 += 64) {
      __syncthreads();
#pragma unroll
      for (int ss = 0; ss < 4; ++ss) {
        int rl = ss * 32 + wave * 8 + lrow;
        int sc = lch ^ (rl & 7);
        async16(Wp + (size_t)(m0 + rl) * 512 + k0 + sc * 8, &As[rl * 64 + lch * 8]);
        async16(Pt + (size_t)(n0 + rl) * 512 + k0 + sc * 8, &Bs[rl * 64 + lch * 8]);
      }
      __syncthreads();
#pragma unroll
      for (int sub = 0; sub < 2; ++sub) {
        int slot = ((sub * 4 + quad) ^ (r16 & 7)) * 8;
        half8 alv = *(const half8*)&Al[k0 + slot];
        half8 af[4], bf[4];
#pragma unroll
        for (int i = 0; i < 4; ++i)
          af[i] = *(const half8*)&As[(wm + i * 16 + r16) * 64 + slot];
#pragma unroll
        for (int j = 0; j < 4; ++j)
          bf[j] = *(const half8*)&Bs[(wn + j * 16 + r16) * 64 + slot] * alv;
#pragma unroll
        for (int i = 0; i < 4; ++i)
#pragma unroll
          for (int j = 0; j < 4; ++j)
            acc[i][j] = __builtin_amdgcn_mfma_f32_16x16x32_f16(af[i], bf[j], acc[i][j], 0, 0, 0);
      }
    }
    bool iskl = (by < 2);
    const float* lgbase = iskl ? logits1 : logits0;
    float local = 0.0f;
#pragma unroll
    for (int i = 0; i < 4; ++i)
#pragma unroll
      for (int r = 0; r < 4; ++r) {
        int Mg = m0 + wm + i * 16 + quad * 4 + r;
        int b = iskl ? Mg : (Mg - 256);
        float mv = mll[iskl ? 256 + b : b];
        const float* lgrow = lgbase + (size_t)b * NS + n0 + wn;
#pragma unroll
        for (int j = 0; j < 4; ++j) {
          float lg = lgrow[j * 16 + r16];
          float t = acc[i][j][r] * (1.0f / 256.0f);
          if (iskl)
            local += (t > 0.0f) ? t * (logf(fmaxf(t, 1e-12f)) - (lg - mv)) : 0.0f;
          else
            local += -0.1f * t * (lg - mv);
        }
      }
    float wsv = waveSum(local);
    if (lane == 0) red[wave] = wsv;
    __syncthreads();
    if (tid == 0) part[nb] = (red[0] + red[1]) + (red[2] + red[3]);
  }
}

// ============ K3: finalize (single block) ============
__global__ __launch_bounds__(256) void final_reduce(
    const float* __restrict__ pm, const float* __restrict__ pl,
    const float* __restrict__ tgt, const float* __restrict__ part,
    const float* __restrict__ logits0, const float* __restrict__ mll,
    const int* __restrict__ targets, const float* __restrict__ rampup,
    float* __restrict__ out) {
  __shared__ float rA[4], rB[4], rC[4], rD[4];
  int tid = threadIdx.x, wave = tid >> 6, lane = tid & 63;
  int b = tid;
  const float* pmb = pm + b * 128;
  const float* plb = pl + b * 128;
  float mx = -1e30f;
  for (int s = 0; s < 128; ++s) mx = fmaxf(mx, pmb[s]);
  float S = 0.0f;
  for (int s = 0; s < 128; ++s) S += plb[s] * expf(pmb[s] - mx);
  float nce = -(tgt[b] - mx - logf(S));
  int tg = targets[b];
  float oh = -0.9f * (logits0[(size_t)b * NS + tg] - mll[b]);
  float c = part[tid];
  float klc = (tid < 128) ? c : 0.0f;
  float cec = (tid < 128) ? 0.0f : c;
  float wn_ = waveSum(nce), wo = waveSum(oh), wk = waveSum(klc), wc = waveSum(cec);
  if (lane == 0) { rA[wave] = wn_; rB[wave] = wo; rC[wave] = wk; rD[wave] = wc; }
  __syncthreads();
  if (tid == 0) {
    float sn = rA[0] + rA[1] + rA[2] + rA[3];
    float so = rB[0] + rB[1] + rB[2] + rB[3];
    float sk = rC[0] + rC[1] + rC[2] + rC[3];
    float sc2 = rD[0] + rD[1] + rD[2] + rD[3];
    out[0] = sn * (1.0f / 256.0f);
    out[1] = (so + sc2) * (1.0f / 256.0f);
    out[2] = rampup[0] * sk * (1.0f / 256.0f);
  }
}

extern "C" void kernel_launch(void* const* d_in, const int* in_sizes, int n_in,
                              void* d_out, int out_size, void* d_ws, size_t ws_size,
                              hipStream_t stream) {
  const float* inputs0 = (const float*)d_in[0];
  const float* logits0 = (const float*)d_in[1];
  const float* logits1 = (const float*)d_in[2];
  const int* targets = (const int*)d_in[3];
  const int* neighbors = (const int*)d_in[5];
  const float* ndist = (const float*)d_in[6];
  const float* rampup = (const float*)d_in[7];
  const float* features = (const float*)d_in[8];
  float* out = (float*)d_out;

  char* ws = (char*)d_ws;
  float* mll = (float*)(ws + 4096);             // 2 KB
  _Float16* alpha_h = (_Float16*)(ws + 8192);   // 1 KB
  float* part = (float*)(ws + 12288);           // 1 KB
  float* tgt = (float*)(ws + 16384);            // 1 KB
  float* pm = (float*)(ws + 65536);             // 128 KB
  float* pl = (float*)(ws + 196608);            // 128 KB
  _Float16* Wp = (_Float16*)(ws + 524288);      // 512 KB
  _Float16* xh = (_Float16*)(ws + (3 << 20));   // 1 MB
  _Float16* Pt = (_Float16*)(ws + (4 << 20));   // 8 MB
  _Float16* fh = (_Float16*)(ws + (12 << 20));  // 32 MB

  prep<<<NS + 1025, 256, 0, stream>>>((const float4*)features, inputs0, logits0,
                                      logits1, targets, neighbors, ndist,
                                      out + 3, fh, Pt, xh, alpha_h, mll, Wp);
  gemms<<<512, 256, 0, stream>>>(xh, fh, Wp, Pt, alpha_h, logits0, logits1, mll,
                                 targets, pm, pl, tgt, part);
  final_reduce<<<1, 256, 0, stream>>>(pm, pl, tgt, part, logits0, mll, targets,
                                      rampup, out);
}